// Round 8
// baseline (199.493 us; speedup 1.0000x reference)
//
#include <hip/hip_runtime.h>
#include <hip/hip_bf16.h>

#define B_   2
#define CIN  384
#define NPIX 3136
#define NH   8
#define KD   16
#define DHEAD 64
#define NHKD 128
#define QKW  256
#define DHD  512
#define EPSW 1e-5f
#define L2E  1.4426950408889634f

typedef __attribute__((ext_vector_type(8))) short vshort8;
typedef __attribute__((ext_vector_type(4))) short vshort4;
typedef __attribute__((ext_vector_type(4))) float vfloat4;
typedef __attribute__((ext_vector_type(16))) float vfloat16;

#if __has_builtin(__builtin_amdgcn_exp2f)
#define EXP2F __builtin_amdgcn_exp2f
#else
#define EXP2F exp2f
#endif

static __device__ __forceinline__ float bf2f(short s) {
    unsigned int u = ((unsigned int)(unsigned short)s) << 16;
    return __builtin_bit_cast(float, u);
}
static __device__ __forceinline__ short f2bf(float f) {
    unsigned int u = __builtin_bit_cast(unsigned int, f);
    unsigned int lsb = (u >> 16) & 1u;
    u += 0x7fffu + lsb;
    return (short)(u >> 16);
}
static __device__ __forceinline__ float pget(const void* p, int i, int f32) {
    return f32 ? ((const float*)p)[i] : bf2f(((const short*)p)[i]);
}

// ---- inline dtype detect: fp32 low-halves carry wild exponent fields -------
static __device__ __forceinline__ int detect_f32(const unsigned short* x) {
    int lane = threadIdx.x & 63;
    bool big = false;
#pragma unroll
    for (int j = 0; j < 8; j++) {
        int e = (x[(lane * 8 + j) * 2] >> 7) & 0xFF;
        big = big || (e >= 0xC0);
    }
    unsigned long long bal = __ballot(big);
    return __popcll(bal) >= 32;
}

// ======= prep: convert weights + BN tables + transpose x, one dispatch ======
__global__ __launch_bounds__(256) void prep_kernel(
    const void* __restrict__ x,
    const void* __restrict__ wq, const void* __restrict__ wk,
    const void* __restrict__ wv, const void* __restrict__ wp,
    short* __restrict__ wB, short* __restrict__ xT,
    const void* qg, const void* qb, const void* qm, const void* qv,
    const void* kg, const void* kb, const void* km, const void* kv,
    const void* vg, const void* vb, const void* vm, const void* vv,
    const void* pg, const void* pb, const void* pm, const void* pv,
    float* __restrict__ scA, float* __restrict__ shA)
{
    __shared__ short tile[32][33];
    int f32 = detect_f32((const unsigned short*)x);
    int id = blockIdx.x;
    int t = threadIdx.x;

    if (id < 1920) {
        int i = id * 256 + t;
        const void* src; int j;
        if (i < 49152)       { src = wq; j = i; }
        else if (i < 98304)  { src = wk; j = i - 49152; }
        else if (i < 294912) { src = wv; j = i - 98304; }
        else                 { src = wp; j = i - 294912; }
        wB[i] = f32 ? f2bf(((const float*)src)[j]) : ((const short*)src)[j];
        if (i < 1152) {
            const void *g, *bb, *mn, *vr;
            if (i < 128)      { g = qg; bb = qb; mn = qm; vr = qv; j = i; }
            else if (i < 256) { g = kg; bb = kb; mn = km; vr = kv; j = i - 128; }
            else if (i < 768) { g = vg; bb = vb; mn = vm; vr = vv; j = i - 256; }
            else              { g = pg; bb = pb; mn = pm; vr = pv; j = i - 768; }
            float iv = rsqrtf(pget(vr, j, f32) + EPSW);
            float s = pget(g, j, f32) * iv;
            float h = pget(bb, j, f32) - pget(mn, j, f32) * s;
            if (i < 128) { s *= L2E; h *= L2E; }   // fold log2(e) into Q path
            scA[i] = s;
            shA[i] = h;
        }
        return;
    }

    int tid2 = id - 1920;                 // transpose job
    int b = tid2 / 1176, rr = tid2 % 1176;
    int n0 = (rr % 98) * 32, c0 = (rr / 98) * 32;
    int r = t >> 3, q4 = (t & 7) * 4;
    size_t off = ((size_t)b * CIN + c0 + r) * NPIX + n0 + q4;
    if (f32) {
        float4 v = *(const float4*)((const float*)x + off);
        tile[r][q4 + 0] = f2bf(v.x);
        tile[r][q4 + 1] = f2bf(v.y);
        tile[r][q4 + 2] = f2bf(v.z);
        tile[r][q4 + 3] = f2bf(v.w);
    } else {
        vshort4 v = *(const vshort4*)((const short*)x + off);
#pragma unroll
        for (int i = 0; i < 4; i++) tile[r][q4 + i] = v[i];
    }
    __syncthreads();
    vshort4 o;
#pragma unroll
    for (int i = 0; i < 4; i++) o[i] = tile[q4 + i][r];
    *(vshort4*)(xT + ((size_t)b * NPIX + n0 + r) * CIN + c0 + q4) = o;
}

// ---- 32x32x16 GEMM body: C(M,N) = A(M,K)·Bt(N,K)^T, block 128x64, 4 waves --
// wave w owns rows w*32..w*32+31, all 64 cols (two 32x32 C-blocks).
// Padded-72 LDS staging (conflict-free, r3-proven); layout verified in attn r7.
static __device__ __forceinline__ void gemm32_body(
    short* Al, short* Bl,
    const short* __restrict__ A, const short* __restrict__ Bt,
    void* __restrict__ C, size_t coff, int m0, int n0,
    const float* __restrict__ sc, const float* __restrict__ sh,
    int Nb, int K, int Mreal, int bnPerRow, int finalOut, int f32)
{
    int t = threadIdx.x, lane = t & 63, w = t >> 6;
    int c31 = lane & 31, half = lane >> 5;
    int arow = t >> 1, ak = (t & 1) * 32;
    int brow = t >> 2, bk = (t & 3) * 16;
    const short* ag = A + (size_t)(m0 + arow) * K + ak;
    const short* bg = Bt + (size_t)(n0 + brow) * K + bk;

    vfloat16 acc0, acc1;
#pragma unroll
    for (int i = 0; i < 16; i++) { acc0[i] = 0.f; acc1[i] = 0.f; }

    for (int k0 = 0; k0 < K; k0 += 64) {
        vshort8 a0 = *(const vshort8*)(ag + k0);
        vshort8 a1 = *(const vshort8*)(ag + k0 + 8);
        vshort8 a2 = *(const vshort8*)(ag + k0 + 16);
        vshort8 a3 = *(const vshort8*)(ag + k0 + 24);
        vshort8 b0 = *(const vshort8*)(bg + k0);
        vshort8 b1 = *(const vshort8*)(bg + k0 + 8);
        __syncthreads();
        *(vshort8*)&Al[arow * 72 + ak]      = a0;
        *(vshort8*)&Al[arow * 72 + ak + 8]  = a1;
        *(vshort8*)&Al[arow * 72 + ak + 16] = a2;
        *(vshort8*)&Al[arow * 72 + ak + 24] = a3;
        *(vshort8*)&Bl[brow * 72 + bk]      = b0;
        *(vshort8*)&Bl[brow * 72 + bk + 8]  = b1;
        __syncthreads();
#pragma unroll
        for (int ks = 0; ks < 4; ks++) {
            vshort8 af  = *(const vshort8*)&Al[(w * 32 + c31) * 72 + ks * 16 + half * 8];
            vshort8 bf0 = *(const vshort8*)&Bl[(c31) * 72 + ks * 16 + half * 8];
            vshort8 bf1 = *(const vshort8*)&Bl[(32 + c31) * 72 + ks * 16 + half * 8];
            acc0 = __builtin_amdgcn_mfma_f32_32x32x16_bf16(af, bf0, acc0, 0, 0, 0);
            acc1 = __builtin_amdgcn_mfma_f32_32x32x16_bf16(af, bf1, acc1, 0, 0, 0);
        }
    }

#pragma unroll
    for (int cb = 0; cb < 2; cb++) {
        int col = n0 + cb * 32 + c31;
        float scc = bnPerRow ? 0.f : sc[col];
        float shc = bnPerRow ? 0.f : sh[col];
#pragma unroll
        for (int r = 0; r < 16; r++) {
            int rowl = (r & 3) + 8 * (r >> 2) + 4 * half;
            int row = m0 + w * 32 + rowl;
            if (row >= Mreal) continue;
            float s2 = bnPerRow ? sc[row] : scc;
            float h2 = bnPerRow ? sh[row] : shc;
            float v = cb ? acc1[r] : acc0[r];
            float val = s2 * v + h2;
            size_t idx = coff + (size_t)row * Nb + col;
            if (finalOut && f32) ((float*)C)[idx] = val;
            else                 ((short*)C)[idx] = f2bf(val);
        }
    }
}

// ======= proj: QK GEMM + V GEMM fused into one dispatch =====================
// blocks [0,200): QKt (3200pad,256) = xT·wqk^T, BN per col, rows<NPIX stored
// blocks [200,592): V (512,N) = wv·xT^T, BN per row
__global__ __launch_bounds__(256) void proj_kernel(
    const short* __restrict__ xT, const short* __restrict__ wqkB,
    const short* __restrict__ wvB, short* __restrict__ QKt,
    short* __restrict__ Vb,
    const float* __restrict__ scA, const float* __restrict__ shA)
{
    __shared__ __attribute__((aligned(16))) short Al[128 * 72];
    __shared__ __attribute__((aligned(16))) short Bl[64 * 72];
    int id = blockIdx.x;
    if (id < 200) {
        int b = id / 100, r = id % 100;
        int m0 = (r % 25) * 128, n0 = (r / 25) * 64;
        gemm32_body(Al, Bl, xT + (size_t)b * NPIX * CIN, wqkB,
                    QKt, (size_t)b * NPIX * QKW, m0, n0,
                    scA, shA, QKW, CIN, NPIX, 0, 0, 0);
    } else {
        id -= 200;
        int b = id / 196, r = id % 196;
        int m0 = (r / 49) * 128, n0 = (r % 49) * 64;
        gemm32_body(Al, Bl, wvB, xT + (size_t)b * NPIX * CIN,
                    Vb, (size_t)b * DHD * NPIX, m0, n0,
                    scA + 256, shA + 256, NPIX, CIN, DHD, 1, 0, 0);
    }
}

// ======= final P GEMM: out (384,N) = wp·relu(xx)^T, dual-dtype store ========
__global__ __launch_bounds__(256) void pgemm_kernel(
    const short* __restrict__ wpB, const short* __restrict__ xx,
    void* __restrict__ out,
    const float* __restrict__ scA, const float* __restrict__ shA,
    const void* __restrict__ x)
{
    __shared__ __attribute__((aligned(16))) short Al[128 * 72];
    __shared__ __attribute__((aligned(16))) short Bl[64 * 72];
    int f32 = detect_f32((const unsigned short*)x);
    int id = blockIdx.x;
    int b = id / 147, r = id % 147;
    int m0 = (r / 49) * 128, n0 = (r % 49) * 64;
    gemm32_body(Al, Bl, wpB, xx + (size_t)b * NPIX * DHD,
                out, (size_t)b * CIN * NPIX, m0, n0,
                scA + 768, shA + 768, NPIX, DHD, CIN, 1, 1, f32);
}

// ======= flash attention v3 (r7-verified) + exp2 fast path ==================
__global__ __launch_bounds__(128) void attn_kernel(
    const short* __restrict__ QKt, const short* __restrict__ V,
    short* __restrict__ xx)
{
    __shared__ __attribute__((aligned(16))) short Kl[2][64 * 16];  // [key][kd]
    __shared__ __attribute__((aligned(16))) short Vl[2][64 * 72];  // [d][key]
    __shared__ __attribute__((aligned(16))) short Pl[64 * 72];     // [q][key]
    int bh = blockIdx.y, b = bh >> 3, h = bh & 7;
    int q0 = blockIdx.x * 64;
    int t = threadIdx.x, lane = t & 63, w = t >> 6;
    int c31 = lane & 31, half = lane >> 5;

    int q = q0 + w * 32 + c31;
    vshort8 aq = *(const vshort8*)(QKt + ((size_t)b * NPIX + q) * QKW + h * KD + half * 8);

    vfloat16 o0, o1, oL, z16;
#pragma unroll
    for (int i = 0; i < 16; i++) { o0[i] = 0.f; o1[i] = 0.f; oL[i] = 0.f; z16[i] = 0.f; }

    int kkey = t >> 1, kofs = (t & 1) * 8;
    const short* kgp = QKt + (size_t)b * NPIX * QKW + NHKD + h * KD + kofs;
    int vd = t >> 1, vkh = (t & 1) * 32;
    const short* vgp = V + ((size_t)(b * DHD) + h * DHEAD + vd) * NPIX + vkh;
    const short one_bf = (short)0x3F80;
    const vshort8 ones = {one_bf, one_bf, one_bf, one_bf, one_bf, one_bf, one_bf, one_bf};

    *(vshort8*)&Kl[0][kkey * 16 + kofs] = *(const vshort8*)(kgp + (size_t)kkey * QKW);
#pragma unroll
    for (int i = 0; i < 4; i++)
        *(vshort8*)&Vl[0][vd * 72 + vkh + i * 8] = *(const vshort8*)(vgp + i * 8);
    __syncthreads();

    for (int it = 0; it < NPIX / 64; ++it) {
        int cur = it & 1, nxt = cur ^ 1;
        int k0 = it * 64;
        bool more = (it + 1) < (NPIX / 64);
        vshort8 ks, vs[4];
        if (more) {
            ks = *(const vshort8*)(kgp + (size_t)(k0 + 64 + kkey) * QKW);
#pragma unroll
            for (int i = 0; i < 4; i++)
                vs[i] = *(const vshort8*)(vgp + k0 + 64 + i * 8);
        }

        // S^T = K·Q^T (scores pre-scaled by log2e) -> p = 2^s, pack to bf16
        short* pw = &Pl[(w * 32 + c31) * 72];
#pragma unroll
        for (int kg = 0; kg < 2; kg++) {
            vshort8 ak = *(const vshort8*)&Kl[cur][(kg * 32 + c31) * 16 + half * 8];
            vfloat16 s = __builtin_amdgcn_mfma_f32_32x32x16_bf16(ak, aq, z16, 0, 0, 0);
#pragma unroll
            for (int rb = 0; rb < 4; rb++) {
                vshort4 pv;
#pragma unroll
                for (int j = 0; j < 4; j++) {
                    float p = EXP2F(s[rb * 4 + j]);
                    pv[j] = (short)(__builtin_bit_cast(unsigned int, p) >> 16);
                }
                *(vshort4*)&pw[kg * 32 + half * 4 + rb * 8] = pv;
            }
        }
        // wave-private P rows: in-order DS pipe -> no barrier write->read

#pragma unroll
        for (int kc = 0; kc < 4; kc++) {
            vshort8 ap  = *(const vshort8*)&Pl[(w * 32 + c31) * 72 + kc * 16 + half * 8];
            vshort8 bv0 = *(const vshort8*)&Vl[cur][(c31) * 72 + kc * 16 + half * 8];
            vshort8 bv1 = *(const vshort8*)&Vl[cur][(32 + c31) * 72 + kc * 16 + half * 8];
            o0 = __builtin_amdgcn_mfma_f32_32x32x16_bf16(ap, bv0, o0, 0, 0, 0);
            o1 = __builtin_amdgcn_mfma_f32_32x32x16_bf16(ap, bv1, o1, 0, 0, 0);
            oL = __builtin_amdgcn_mfma_f32_32x32x16_bf16(ap, ones, oL, 0, 0, 0);
        }

        if (more) {
            *(vshort8*)&Kl[nxt][kkey * 16 + kofs] = ks;
#pragma unroll
            for (int i = 0; i < 4; i++)
                *(vshort8*)&Vl[nxt][vd * 72 + vkh + i * 8] = vs[i];
        }
        __syncthreads();
    }

#pragma unroll
    for (int r = 0; r < 16; r++) {
        int ql = (r & 3) + 8 * (r >> 2) + 4 * half;
        int qrow = q0 + w * 32 + ql;
        float inv = 1.0f / oL[r];
        size_t base = ((size_t)b * NPIX + qrow) * DHD + h * DHEAD + c31;
        xx[base]      = f2bf(fmaxf(o0[r] * inv, 0.f));
        xx[base + 32] = f2bf(fmaxf(o1[r] * inv, 0.f));
    }
}

extern "C" void kernel_launch(void* const* d_in, const int* in_sizes, int n_in,
                              void* d_out, int out_size, void* d_ws, size_t ws_size,
                              hipStream_t stream) {
    const void* x  = d_in[0];
    const void* wq = d_in[1];
    const void* qg = d_in[2];  const void* qb = d_in[3];
    const void* qm = d_in[4];  const void* qv = d_in[5];
    const void* wk = d_in[6];
    const void* kg = d_in[7];  const void* kb = d_in[8];
    const void* km = d_in[9];  const void* kv = d_in[10];
    const void* wv = d_in[11];
    const void* vg = d_in[12]; const void* vb = d_in[13];
    const void* vm = d_in[14]; const void* vv = d_in[15];
    const void* wp = d_in[16];
    const void* pg = d_in[17]; const void* pb = d_in[18];
    const void* pm = d_in[19]; const void* pv = d_in[20];

    short* xT  = (short*)d_ws;                           // (B,N,384) bf16
    short* wB  = xT + (size_t)B_ * NPIX * CIN;           // wq|wk|wv|wp bf16
    short* wqkB = wB;                                    // 256 x 384
    short* wvB  = wB + 98304;                            // 512 x 384
    short* wpB  = wB + 294912;                           // 384 x 512
    short* QKt = wB + 491520;                            // (B,N,256)
    short* Vb  = QKt + (size_t)B_ * NPIX * QKW;          // (B,512,N)
    short* xx  = Vb + (size_t)B_ * DHD * NPIX;           // (B,N,512)
    float* scA = (float*)(xx + (size_t)B_ * NPIX * DHD); // 1152 fp32
    float* shA = scA + 1152;

    prep_kernel<<<4272, 256, 0, stream>>>(
        x, wq, wk, wv, wp, wB, xT,
        qg, qb, qm, qv, kg, kb, km, kv,
        vg, vb, vm, vv, pg, pb, pm, pv, scA, shA);

    proj_kernel<<<592, 256, 0, stream>>>(xT, wqkB, wvB, QKt, Vb, scA, shA);

    attn_kernel<<<dim3(NPIX / 64, B_ * NH), 128, 0, stream>>>(QKt, Vb, xx);

    pgemm_kernel<<<294, 256, 0, stream>>>(wpB, xx, d_out, scA, shA, x);
}